// Round 1
// baseline (345.137 us; speedup 1.0000x reference)
//
#include <hip/hip_runtime.h>
#include <math.h>

#define N_FEAT 8192
#define DIM 512
#define KC 64
#define MF 128
#define TF 32
#define SLOTS 16

__device__ __forceinline__ float wave_reduce_sum(float s) {
#pragma unroll
  for (int o = 32; o; o >>= 1) s += __shfl_xor(s, o);
  return s;
}

// Kernel A0: row squared norms for coarse (64 rows) and fine (8192 rows).
__global__ void __launch_bounds__(64) rownorm_kernel(
    const float* __restrict__ coarse, const float* __restrict__ fine,
    float* __restrict__ c2, float* __restrict__ p2) {
  int r = blockIdx.x;
  const float* src = (r < KC) ? (coarse + (size_t)r * DIM)
                              : (fine + (size_t)(r - KC) * DIM);
  int l = threadIdx.x;
  const float* p = src + l * 8;
  float4 a = *(const float4*)p;
  float4 b = *(const float4*)(p + 4);
  float s = a.x * a.x + a.y * a.y + a.z * a.z + a.w * a.w +
            b.x * b.x + b.y * b.y + b.z * b.z + b.w * b.w;
  s = wave_reduce_sum(s);
  if (l == 0) {
    if (r < KC) c2[r] = s;
    else        p2[r - KC] = s;
  }
}

// Kernel A: coarse assignment. One wave handles 4 features.
// argmin_k (||c_k||^2 - 2 f.c_k)  (f^2 term constant per row).
__global__ void __launch_bounds__(64) assign_kernel(
    const float* __restrict__ feat, const float* __restrict__ coarse,
    const float* __restrict__ c2, float* __restrict__ f2,
    int* __restrict__ assign, int* __restrict__ counts) {
  int l = threadIdx.x;
  int n0 = blockIdx.x * 4;
  float fr[4][8];
#pragma unroll
  for (int a = 0; a < 4; a++) {
    const float* p = feat + (size_t)(n0 + a) * DIM + l * 8;
    float4 x = *(const float4*)p;
    float4 y = *(const float4*)(p + 4);
    fr[a][0] = x.x; fr[a][1] = x.y; fr[a][2] = x.z; fr[a][3] = x.w;
    fr[a][4] = y.x; fr[a][5] = y.y; fr[a][6] = y.z; fr[a][7] = y.w;
  }
#pragma unroll
  for (int a = 0; a < 4; a++) {
    float s = 0.f;
#pragma unroll
    for (int j = 0; j < 8; j++) s = fmaf(fr[a][j], fr[a][j], s);
    s = wave_reduce_sum(s);
    if (l == a) f2[n0 + a] = s;
  }
  float c2l = c2[l];
  float best[4] = {1e30f, 1e30f, 1e30f, 1e30f};
  int bk[4] = {0, 0, 0, 0};
  for (int k = 0; k < KC; k++) {
    const float* p = coarse + (size_t)k * DIM + l * 8;
    float4 x = *(const float4*)p;
    float4 y = *(const float4*)(p + 4);
    float cc[8] = {x.x, x.y, x.z, x.w, y.x, y.y, y.z, y.w};
    float c2k = __shfl(c2l, k);
#pragma unroll
    for (int a = 0; a < 4; a++) {
      float s = 0.f;
#pragma unroll
      for (int j = 0; j < 8; j++) s = fmaf(fr[a][j], cc[j], s);
      s = wave_reduce_sum(s);
      float d2 = c2k - 2.f * s;
      if (d2 < best[a]) { best[a] = d2; bk[a] = k; }  // strict < : first-min wins, matches argmin
    }
  }
  if (l == 0) {
#pragma unroll
    for (int a = 0; a < 4; a++) {
      assign[n0 + a] = bk[a];
      atomicAdd(&counts[bk[a]], 1);
    }
  }
}

// Kernel B1: exclusive prefix sum of 64 cluster counts (one wave).
__global__ void __launch_bounds__(64) scan_kernel(const int* __restrict__ counts,
                                                  int* __restrict__ offsets) {
  int l = threadIdx.x;
  int c = counts[l];
  int s = c;
#pragma unroll
  for (int o = 1; o < 64; o <<= 1) {
    int v = __shfl_up(s, o);
    if (l >= o) s += v;
  }
  offsets[l] = s - c;
}

// Kernel B2: scatter feature indices into per-cluster buckets.
__global__ void __launch_bounds__(256) scatter_kernel(
    const int* __restrict__ assign, const int* __restrict__ offsets,
    int* __restrict__ fill, int* __restrict__ order) {
  int n = blockIdx.x * blockDim.x + threadIdx.x;
  int k = assign[n];
  int pos = atomicAdd(&fill[k], 1);
  order[offsets[k] + pos] = n;
}

// Kernel C: per-cluster fine distances + min + mean accumulation.
// Block = (cluster k, tile slot). Tile = 32 features x 128 prototypes x D=512.
// 256 threads, each computes a 2(f) x 8(m) register tile.
__global__ void __launch_bounds__(256) fine_kernel(
    const float* __restrict__ feat, const float* __restrict__ fine,
    const float* __restrict__ f2, const float* __restrict__ p2,
    const int* __restrict__ counts, const int* __restrict__ offsets,
    const int* __restrict__ order, float* __restrict__ out) {
  int k = blockIdx.x & (KC - 1);
  int slot = blockIdx.x >> 6;
  int nk = counts[k];
  int ntiles = (nk + TF - 1) / TF;

  __shared__ float fs[32][TF + 2];    // [d][f], stride 34 keeps float2 8B-aligned
  __shared__ float ps[32][MF + 4];    // [d][m], stride 132 keeps float4 16B-aligned
  __shared__ float red[TF][17];       // per-feature mins across 16 m-groups

  int t = threadIdx.x;
  int fi = (t & 15) * 2;   // feature offset in tile (0..30)
  int mg = t >> 4;         // m-group 0..15
  int mi = mg * 8;         // prototype offset (0..120)
  int fl = t >> 3;         // staging row 0..31
  int dl = (t & 7) * 4;    // staging d offset (float4)
  int base = offsets[k];

  float p2v[8];
#pragma unroll
  for (int j = 0; j < 8; j++) p2v[j] = p2[k * MF + mi + j];

  for (int tile = slot; tile < ntiles; tile += SLOTS) {
    int f0 = tile * TF;
    int nf = min(TF, nk - f0);          // >=1 inside loop
    int gf = order[base + f0 + min(fl, nf - 1)];

    float acc[2][8];
#pragma unroll
    for (int u = 0; u < 2; u++)
#pragma unroll
      for (int j = 0; j < 8; j++) acc[u][j] = 0.f;

    for (int dc = 0; dc < DIM; dc += 32) {
      // stage features (32 rows x 32 d)
      float4 v = *(const float4*)(feat + (size_t)gf * DIM + dc + dl);
      fs[dl + 0][fl] = v.x; fs[dl + 1][fl] = v.y;
      fs[dl + 2][fl] = v.z; fs[dl + 3][fl] = v.w;
      // stage prototypes (128 rows x 32 d), 4 passes of 32 rows
#pragma unroll
      for (int pass = 0; pass < 4; pass++) {
        int ml = pass * 32 + fl;
        float4 w = *(const float4*)(fine + ((size_t)k * MF + ml) * DIM + dc + dl);
        ps[dl + 0][ml] = w.x; ps[dl + 1][ml] = w.y;
        ps[dl + 2][ml] = w.z; ps[dl + 3][ml] = w.w;
      }
      __syncthreads();
#pragma unroll
      for (int dd = 0; dd < 32; dd++) {
        float2 fv = *(const float2*)&fs[dd][fi];
        float4 p0 = *(const float4*)&ps[dd][mi];
        float4 p1 = *(const float4*)&ps[dd][mi + 4];
        acc[0][0] = fmaf(fv.x, p0.x, acc[0][0]);
        acc[0][1] = fmaf(fv.x, p0.y, acc[0][1]);
        acc[0][2] = fmaf(fv.x, p0.z, acc[0][2]);
        acc[0][3] = fmaf(fv.x, p0.w, acc[0][3]);
        acc[0][4] = fmaf(fv.x, p1.x, acc[0][4]);
        acc[0][5] = fmaf(fv.x, p1.y, acc[0][5]);
        acc[0][6] = fmaf(fv.x, p1.z, acc[0][6]);
        acc[0][7] = fmaf(fv.x, p1.w, acc[0][7]);
        acc[1][0] = fmaf(fv.y, p0.x, acc[1][0]);
        acc[1][1] = fmaf(fv.y, p0.y, acc[1][1]);
        acc[1][2] = fmaf(fv.y, p0.z, acc[1][2]);
        acc[1][3] = fmaf(fv.y, p0.w, acc[1][3]);
        acc[1][4] = fmaf(fv.y, p1.x, acc[1][4]);
        acc[1][5] = fmaf(fv.y, p1.y, acc[1][5]);
        acc[1][6] = fmaf(fv.y, p1.z, acc[1][6]);
        acc[1][7] = fmaf(fv.y, p1.w, acc[1][7]);
      }
      __syncthreads();
    }

    // epilogue: d2 = f2 + p2 - 2 dot; min over this thread's 8 m per feature
    float f2a = (fi < nf)     ? f2[order[base + f0 + fi]]     : 0.f;
    float f2b = (fi + 1 < nf) ? f2[order[base + f0 + fi + 1]] : 0.f;
    float m0 = 1e30f, m1 = 1e30f;
#pragma unroll
    for (int j = 0; j < 8; j++) {
      m0 = fminf(m0, f2a + p2v[j] - 2.f * acc[0][j]);
      m1 = fminf(m1, f2b + p2v[j] - 2.f * acc[1][j]);
    }
    red[fi][mg] = m0;
    red[fi + 1][mg] = m1;
    __syncthreads();
    if (t < 64) {
      float val = 0.f;
      if (t < nf) {  // nf <= 32, so only valid rows of red are read
        float m = red[t][0];
#pragma unroll
        for (int g = 1; g < 16; g++) m = fminf(m, red[t][g]);
        val = sqrtf(fmaxf(m, 0.f)) * (1.0f / (float)N_FEAT);
      }
      val = wave_reduce_sum(val);
      if (t == 0) atomicAdd(out, val);
    }
    __syncthreads();
  }
}

extern "C" void kernel_launch(void* const* d_in, const int* in_sizes, int n_in,
                              void* d_out, int out_size, void* d_ws, size_t ws_size,
                              hipStream_t stream) {
  (void)in_sizes; (void)n_in; (void)out_size; (void)ws_size;
  const float* feat   = (const float*)d_in[0];
  const float* coarse = (const float*)d_in[1];
  const float* fine   = (const float*)d_in[2];
  float* out = (float*)d_out;

  float* f2      = (float*)d_ws;            // 8192
  float* c2      = f2 + N_FEAT;             // 64
  float* p2      = c2 + KC;                 // 8192
  int*   assign  = (int*)(p2 + KC * MF);    // 8192
  int*   counts  = assign + N_FEAT;         // 64
  int*   fill    = counts + KC;             // 64 (contiguous with counts)
  int*   offsets = fill + KC;               // 64
  int*   order   = offsets + KC;            // 8192

  hipMemsetAsync(out, 0, sizeof(float), stream);
  hipMemsetAsync(counts, 0, 2 * KC * sizeof(int), stream);  // counts + fill

  rownorm_kernel<<<KC + KC * MF, 64, 0, stream>>>(coarse, fine, c2, p2);
  assign_kernel<<<N_FEAT / 4, 64, 0, stream>>>(feat, coarse, c2, f2, assign, counts);
  scan_kernel<<<1, 64, 0, stream>>>(counts, offsets);
  scatter_kernel<<<N_FEAT / 256, 256, 0, stream>>>(assign, offsets, fill, order);
  fine_kernel<<<KC * SLOTS, 256, 0, stream>>>(feat, fine, f2, p2, counts, offsets, order, out);
}

// Round 2
// 160.630 us; speedup vs baseline: 2.1487x; 2.1487x over previous
//
#include <hip/hip_runtime.h>
#include <math.h>

#define N_FEAT 8192
#define DIM 512
#define KC 64
#define MF 128
#define TFT 32
#define MAXTILES 320   // sum ceil(nk/32) <= 8192/32 + 64 = 320

__device__ __forceinline__ float wave_reduce_sum(float s) {
#pragma unroll
  for (int o = 32; o; o >>= 1) s += __shfl_xor(s, o);
  return s;
}

// All row squared-norms in one kernel: features (f2), coarse (c2), fine (p2).
__global__ void __launch_bounds__(256) rownorm_kernel(
    const float* __restrict__ feat, const float* __restrict__ coarse,
    const float* __restrict__ fine, float* __restrict__ f2,
    float* __restrict__ c2, float* __restrict__ p2) {
  int r = blockIdx.x * 4 + (threadIdx.x >> 6);
  int l = threadIdx.x & 63;
  const float* src;
  float* dst;
  if (r < N_FEAT) { src = feat + (size_t)r * DIM; dst = f2 + r; }
  else if (r < N_FEAT + KC) { src = coarse + (size_t)(r - N_FEAT) * DIM; dst = c2 + (r - N_FEAT); }
  else { src = fine + (size_t)(r - N_FEAT - KC) * DIM; dst = p2 + (r - N_FEAT - KC); }
  const float* p = src + l * 8;
  float4 a = *(const float4*)p;
  float4 b = *(const float4*)(p + 4);
  float s = a.x * a.x + a.y * a.y + a.z * a.z + a.w * a.w +
            b.x * b.x + b.y * b.y + b.z * b.z + b.w * b.w;
  s = wave_reduce_sum(s);
  if (l == 0) *dst = s;
}

// Coarse assignment as a tiled GEMM: 32 features x 64 clusters per block.
// Double-buffered LDS, 2f x 4k register tile per thread, argmin epilogue.
__global__ void __launch_bounds__(256) assign_kernel(
    const float* __restrict__ feat, const float* __restrict__ coarse,
    const float* __restrict__ c2, int* __restrict__ assign,
    int* __restrict__ counts) {
  __shared__ float fs[2][32][34];   // [buf][d][f]
  __shared__ float cs[2][32][68];   // [buf][d][k]
  __shared__ float rv[32][17];
  __shared__ int ri[32][17];

  int t = threadIdx.x;
  int n0 = blockIdx.x * 32;
  int fi = (t & 15) * 2;            // feature 0..30
  int kg = t >> 4;                  // k-group 0..15
  int ki = kg * 4;
  int fl = t >> 3, dl = (t & 7) * 4;    // feature staging: 32 rows x 8 d-slots
  int kl = t >> 2, dl2 = (t & 3) * 8;   // coarse staging: 64 rows x 4 d-slots

  const float* frow = feat + (size_t)(n0 + fl) * DIM;
  const float* crow = coarse + (size_t)kl * DIM;

  float c2v[4];
#pragma unroll
  for (int j = 0; j < 4; j++) c2v[j] = c2[ki + j];

  float4 vf = *(const float4*)(frow + dl);
  float4 vc0 = *(const float4*)(crow + dl2);
  float4 vc1 = *(const float4*)(crow + dl2 + 4);
  fs[0][dl + 0][fl] = vf.x; fs[0][dl + 1][fl] = vf.y;
  fs[0][dl + 2][fl] = vf.z; fs[0][dl + 3][fl] = vf.w;
  cs[0][dl2 + 0][kl] = vc0.x; cs[0][dl2 + 1][kl] = vc0.y;
  cs[0][dl2 + 2][kl] = vc0.z; cs[0][dl2 + 3][kl] = vc0.w;
  cs[0][dl2 + 4][kl] = vc1.x; cs[0][dl2 + 5][kl] = vc1.y;
  cs[0][dl2 + 6][kl] = vc1.z; cs[0][dl2 + 7][kl] = vc1.w;

  float acc[2][4] = {{0.f, 0.f, 0.f, 0.f}, {0.f, 0.f, 0.f, 0.f}};

  for (int c = 0; c < 16; c++) {
    int cur = c & 1;
    if (c < 15) {   // prefetch next chunk into registers (latency hides under FMAs)
      int dc = (c + 1) * 32;
      vf = *(const float4*)(frow + dc + dl);
      vc0 = *(const float4*)(crow + dc + dl2);
      vc1 = *(const float4*)(crow + dc + dl2 + 4);
    }
    __syncthreads();
#pragma unroll
    for (int dd = 0; dd < 32; dd++) {
      float2 fv = *(const float2*)&fs[cur][dd][fi];
      float4 cv = *(const float4*)&cs[cur][dd][ki];
      acc[0][0] = fmaf(fv.x, cv.x, acc[0][0]);
      acc[0][1] = fmaf(fv.x, cv.y, acc[0][1]);
      acc[0][2] = fmaf(fv.x, cv.z, acc[0][2]);
      acc[0][3] = fmaf(fv.x, cv.w, acc[0][3]);
      acc[1][0] = fmaf(fv.y, cv.x, acc[1][0]);
      acc[1][1] = fmaf(fv.y, cv.y, acc[1][1]);
      acc[1][2] = fmaf(fv.y, cv.z, acc[1][2]);
      acc[1][3] = fmaf(fv.y, cv.w, acc[1][3]);
    }
    if (c < 15) {   // write prefetched regs to the other buffer (no extra barrier)
      int nb = cur ^ 1;
      fs[nb][dl + 0][fl] = vf.x; fs[nb][dl + 1][fl] = vf.y;
      fs[nb][dl + 2][fl] = vf.z; fs[nb][dl + 3][fl] = vf.w;
      cs[nb][dl2 + 0][kl] = vc0.x; cs[nb][dl2 + 1][kl] = vc0.y;
      cs[nb][dl2 + 2][kl] = vc0.z; cs[nb][dl2 + 3][kl] = vc0.w;
      cs[nb][dl2 + 4][kl] = vc1.x; cs[nb][dl2 + 5][kl] = vc1.y;
      cs[nb][dl2 + 6][kl] = vc1.z; cs[nb][dl2 + 7][kl] = vc1.w;
    }
  }

  // argmin_k (c2[k] - 2 f.c): ascending scan, strict < -> first-min (matches argmin)
#pragma unroll
  for (int u = 0; u < 2; u++) {
    float bv = 1e30f;
    int bi = 0;
#pragma unroll
    for (int j = 0; j < 4; j++) {
      float v = c2v[j] - 2.f * acc[u][j];
      if (v < bv) { bv = v; bi = ki + j; }
    }
    rv[fi + u][kg] = bv;
    ri[fi + u][kg] = bi;
  }
  __syncthreads();
  if (t < 32) {
    float bv = rv[t][0];
    int bi = ri[t][0];
#pragma unroll
    for (int g = 1; g < 16; g++) {
      float v = rv[t][g];
      int i2 = ri[t][g];
      if (v < bv || (v == bv && i2 < bi)) { bv = v; bi = i2; }
    }
    assign[n0 + t] = bi;
    atomicAdd(&counts[bi], 1);
  }
}

// Prefix sums + exact fine-tile worklist (one wave).
__global__ void __launch_bounds__(64) scan_tiles_kernel(
    const int* __restrict__ counts, int* __restrict__ offsets,
    int* __restrict__ tlist, int* __restrict__ ntt) {
  int l = threadIdx.x;
  int c = counts[l];
  int s = c;
#pragma unroll
  for (int o = 1; o < 64; o <<= 1) {
    int v = __shfl_up(s, o);
    if (l >= o) s += v;
  }
  offsets[l] = s - c;
  int nt = (c + TFT - 1) / TFT;
  int s2 = nt;
#pragma unroll
  for (int o = 1; o < 64; o <<= 1) {
    int v = __shfl_up(s2, o);
    if (l >= o) s2 += v;
  }
  int tb = s2 - nt;
  if (l == 63) ntt[0] = s2;
  for (int tt = 0; tt < nt; tt++) tlist[tb + tt] = (l << 16) | tt;
}

__global__ void __launch_bounds__(256) scatter_kernel(
    const int* __restrict__ assign, const int* __restrict__ offsets,
    int* __restrict__ fill, int* __restrict__ order) {
  int n = blockIdx.x * blockDim.x + threadIdx.x;
  int k = assign[n];
  int pos = atomicAdd(&fill[k], 1);
  order[offsets[k] + pos] = n;
}

// Fine distances: one block per worklist tile (32 features x 128 protos x D=512).
// Double-buffered reg-staged LDS pipeline; 2f x 8m register tile per thread.
__global__ void __launch_bounds__(256) fine_kernel(
    const float* __restrict__ feat, const float* __restrict__ fine,
    const float* __restrict__ f2, const float* __restrict__ p2,
    const int* __restrict__ counts, const int* __restrict__ offsets,
    const int* __restrict__ order, const int* __restrict__ tlist,
    const int* __restrict__ ntt, float* __restrict__ out) {
  int bid = blockIdx.x;
  if (bid >= ntt[0]) return;
  int code = tlist[bid];
  int k = code >> 16;
  int tile = code & 0xffff;
  int nk = counts[k];
  int base = offsets[k];
  int f0 = tile * TFT;
  int nf = min(TFT, nk - f0);   // >= 1 by construction

  __shared__ float fs[2][32][34];    // [buf][d][f]
  __shared__ float ps[2][32][132];   // [buf][d][m]
  __shared__ float red[32][17];

  int t = threadIdx.x;
  int fi = (t & 15) * 2;
  int mg = t >> 4;
  int mi = mg * 8;
  int fl = t >> 3, dl = (t & 7) * 4;

  int gf = order[base + f0 + min(fl, nf - 1)];
  const float* frow = feat + (size_t)gf * DIM;
  const float* prow = fine + ((size_t)k * MF) * DIM;

  float p2v[8];
#pragma unroll
  for (int j = 0; j < 8; j++) p2v[j] = p2[k * MF + mi + j];

  float4 vf = *(const float4*)(frow + dl);
  float4 vp[4];
#pragma unroll
  for (int pass = 0; pass < 4; pass++)
    vp[pass] = *(const float4*)(prow + (size_t)(pass * 32 + fl) * DIM + dl);

  fs[0][dl + 0][fl] = vf.x; fs[0][dl + 1][fl] = vf.y;
  fs[0][dl + 2][fl] = vf.z; fs[0][dl + 3][fl] = vf.w;
#pragma unroll
  for (int pass = 0; pass < 4; pass++) {
    int ml = pass * 32 + fl;
    ps[0][dl + 0][ml] = vp[pass].x; ps[0][dl + 1][ml] = vp[pass].y;
    ps[0][dl + 2][ml] = vp[pass].z; ps[0][dl + 3][ml] = vp[pass].w;
  }

  float acc[2][8];
#pragma unroll
  for (int u = 0; u < 2; u++)
#pragma unroll
    for (int j = 0; j < 8; j++) acc[u][j] = 0.f;

  for (int c = 0; c < 16; c++) {
    int cur = c & 1;
    if (c < 15) {
      int dc = (c + 1) * 32;
      vf = *(const float4*)(frow + dc + dl);
#pragma unroll
      for (int pass = 0; pass < 4; pass++)
        vp[pass] = *(const float4*)(prow + (size_t)(pass * 32 + fl) * DIM + dc + dl);
    }
    __syncthreads();
#pragma unroll
    for (int dd = 0; dd < 32; dd++) {
      float2 fv = *(const float2*)&fs[cur][dd][fi];
      float4 p0 = *(const float4*)&ps[cur][dd][mi];
      float4 p1 = *(const float4*)&ps[cur][dd][mi + 4];
      acc[0][0] = fmaf(fv.x, p0.x, acc[0][0]);
      acc[0][1] = fmaf(fv.x, p0.y, acc[0][1]);
      acc[0][2] = fmaf(fv.x, p0.z, acc[0][2]);
      acc[0][3] = fmaf(fv.x, p0.w, acc[0][3]);
      acc[0][4] = fmaf(fv.x, p1.x, acc[0][4]);
      acc[0][5] = fmaf(fv.x, p1.y, acc[0][5]);
      acc[0][6] = fmaf(fv.x, p1.z, acc[0][6]);
      acc[0][7] = fmaf(fv.x, p1.w, acc[0][7]);
      acc[1][0] = fmaf(fv.y, p0.x, acc[1][0]);
      acc[1][1] = fmaf(fv.y, p0.y, acc[1][1]);
      acc[1][2] = fmaf(fv.y, p0.z, acc[1][2]);
      acc[1][3] = fmaf(fv.y, p0.w, acc[1][3]);
      acc[1][4] = fmaf(fv.y, p1.x, acc[1][4]);
      acc[1][5] = fmaf(fv.y, p1.y, acc[1][5]);
      acc[1][6] = fmaf(fv.y, p1.z, acc[1][6]);
      acc[1][7] = fmaf(fv.y, p1.w, acc[1][7]);
    }
    if (c < 15) {
      int nb = cur ^ 1;
      fs[nb][dl + 0][fl] = vf.x; fs[nb][dl + 1][fl] = vf.y;
      fs[nb][dl + 2][fl] = vf.z; fs[nb][dl + 3][fl] = vf.w;
#pragma unroll
      for (int pass = 0; pass < 4; pass++) {
        int ml = pass * 32 + fl;
        ps[nb][dl + 0][ml] = vp[pass].x; ps[nb][dl + 1][ml] = vp[pass].y;
        ps[nb][dl + 2][ml] = vp[pass].z; ps[nb][dl + 3][ml] = vp[pass].w;
      }
    }
  }

  // d2 = f2 + p2 - 2 dot; min over this thread's 8 m per feature
  float f2a = (fi < nf) ? f2[order[base + f0 + fi]] : 0.f;
  float f2b = (fi + 1 < nf) ? f2[order[base + f0 + fi + 1]] : 0.f;
  float m0 = 1e30f, m1 = 1e30f;
#pragma unroll
  for (int j = 0; j < 8; j++) {
    m0 = fminf(m0, f2a + p2v[j] - 2.f * acc[0][j]);
    m1 = fminf(m1, f2b + p2v[j] - 2.f * acc[1][j]);
  }
  red[fi][mg] = m0;
  red[fi + 1][mg] = m1;
  __syncthreads();
  if (t < 64) {
    float val = 0.f;
    if (t < nf) {
      float m = red[t][0];
#pragma unroll
      for (int g = 1; g < 16; g++) m = fminf(m, red[t][g]);
      val = sqrtf(fmaxf(m, 0.f)) * (1.0f / (float)N_FEAT);
    }
    val = wave_reduce_sum(val);
    if (t == 0) atomicAdd(out, val);
  }
}

extern "C" void kernel_launch(void* const* d_in, const int* in_sizes, int n_in,
                              void* d_out, int out_size, void* d_ws, size_t ws_size,
                              hipStream_t stream) {
  (void)in_sizes; (void)n_in; (void)out_size; (void)ws_size;
  const float* feat   = (const float*)d_in[0];
  const float* coarse = (const float*)d_in[1];
  const float* fine   = (const float*)d_in[2];
  float* out = (float*)d_out;

  float* f2      = (float*)d_ws;            // 8192
  float* c2      = f2 + N_FEAT;             // 64
  float* p2      = c2 + KC;                 // 8192
  int*   assign  = (int*)(p2 + KC * MF);    // 8192
  int*   counts  = assign + N_FEAT;         // 64
  int*   fill    = counts + KC;             // 64 (contiguous with counts)
  int*   offsets = fill + KC;               // 64
  int*   order   = offsets + KC;            // 8192
  int*   tlist   = order + N_FEAT;          // 320
  int*   ntt     = tlist + MAXTILES;        // 1

  hipMemsetAsync(out, 0, sizeof(float), stream);
  hipMemsetAsync(counts, 0, 2 * KC * sizeof(int), stream);  // counts + fill

  rownorm_kernel<<<(N_FEAT + KC + KC * MF) / 4, 256, 0, stream>>>(
      feat, coarse, fine, f2, c2, p2);
  assign_kernel<<<N_FEAT / 32, 256, 0, stream>>>(feat, coarse, c2, assign, counts);
  scan_tiles_kernel<<<1, 64, 0, stream>>>(counts, offsets, tlist, ntt);
  scatter_kernel<<<N_FEAT / 256, 256, 0, stream>>>(assign, offsets, fill, order);
  fine_kernel<<<MAXTILES, 256, 0, stream>>>(feat, fine, f2, p2, counts, offsets,
                                            order, tlist, ntt, out);
}

// Round 3
// 104.896 us; speedup vs baseline: 3.2903x; 1.5313x over previous
//
#include <hip/hip_runtime.h>
#include <math.h>
#include <stdint.h>

#define N_FEAT 8192
#define DIM 512
#define KC 64
#define MF 128
#define TFT 32
#define MAXTILES 320   // sum ceil(nk/32) <= 8192/32 + 64 = 320
#define BKC 64         // d-chunk for fine mfma
#define NCH (DIM / BKC)

typedef __attribute__((ext_vector_type(8))) short bf16x8;
typedef __attribute__((ext_vector_type(4))) float f32x4;

__device__ __forceinline__ float wave_reduce_sum(float s) {
#pragma unroll
  for (int o = 32; o; o >>= 1) s += __shfl_xor(s, o);
  return s;
}

__device__ __forceinline__ unsigned short f2bf(float x) {  // RTNE f32->bf16
  uint32_t u = __float_as_uint(x);
  return (unsigned short)((u + 0x7fffu + ((u >> 16) & 1u)) >> 16);
}

// Prep: convert feat+fine to bf16 (ws) and compute f2/c2/p2 row norms (f32, exact).
__global__ void __launch_bounds__(256) prep_kernel(
    const float* __restrict__ feat, const float* __restrict__ coarse,
    const float* __restrict__ fine, unsigned short* __restrict__ feat_bf,
    unsigned short* __restrict__ fine_bf, float* __restrict__ f2,
    float* __restrict__ c2, float* __restrict__ p2) {
  int r = blockIdx.x * 4 + (threadIdx.x >> 6);
  int l = threadIdx.x & 63;
  const float* src;
  unsigned short* dstb = nullptr;
  float* dstn;
  if (r < N_FEAT) {
    src = feat + (size_t)r * DIM; dstb = feat_bf + (size_t)r * DIM; dstn = f2 + r;
  } else if (r < N_FEAT + KC) {
    src = coarse + (size_t)(r - N_FEAT) * DIM; dstn = c2 + (r - N_FEAT);
  } else {
    int rr = r - N_FEAT - KC;
    src = fine + (size_t)rr * DIM; dstb = fine_bf + (size_t)rr * DIM; dstn = p2 + rr;
  }
  float4 a = *(const float4*)(src + l * 8);
  float4 b = *(const float4*)(src + l * 8 + 4);
  float s = a.x * a.x + a.y * a.y + a.z * a.z + a.w * a.w +
            b.x * b.x + b.y * b.y + b.z * b.z + b.w * b.w;
  if (dstb) {
    union { unsigned short u[8]; uint4 v; } o;
    o.u[0] = f2bf(a.x); o.u[1] = f2bf(a.y); o.u[2] = f2bf(a.z); o.u[3] = f2bf(a.w);
    o.u[4] = f2bf(b.x); o.u[5] = f2bf(b.y); o.u[6] = f2bf(b.z); o.u[7] = f2bf(b.w);
    *(uint4*)(dstb + l * 8) = o.v;
  }
  s = wave_reduce_sum(s);
  if (l == 0) *dstn = s;
}

// Coarse assignment (exact f32, unchanged from round 2): 32f x 64k tiled GEMM.
__global__ void __launch_bounds__(256) assign_kernel(
    const float* __restrict__ feat, const float* __restrict__ coarse,
    const float* __restrict__ c2, int* __restrict__ assign,
    int* __restrict__ counts) {
  __shared__ float fs[2][32][34];
  __shared__ float cs[2][32][68];
  __shared__ float rv[32][17];
  __shared__ int ri[32][17];

  int t = threadIdx.x;
  int n0 = blockIdx.x * 32;
  int fi = (t & 15) * 2;
  int kg = t >> 4;
  int ki = kg * 4;
  int fl = t >> 3, dl = (t & 7) * 4;
  int kl = t >> 2, dl2 = (t & 3) * 8;

  const float* frow = feat + (size_t)(n0 + fl) * DIM;
  const float* crow = coarse + (size_t)kl * DIM;

  float c2v[4];
#pragma unroll
  for (int j = 0; j < 4; j++) c2v[j] = c2[ki + j];

  float4 vf = *(const float4*)(frow + dl);
  float4 vc0 = *(const float4*)(crow + dl2);
  float4 vc1 = *(const float4*)(crow + dl2 + 4);
  fs[0][dl + 0][fl] = vf.x; fs[0][dl + 1][fl] = vf.y;
  fs[0][dl + 2][fl] = vf.z; fs[0][dl + 3][fl] = vf.w;
  cs[0][dl2 + 0][kl] = vc0.x; cs[0][dl2 + 1][kl] = vc0.y;
  cs[0][dl2 + 2][kl] = vc0.z; cs[0][dl2 + 3][kl] = vc0.w;
  cs[0][dl2 + 4][kl] = vc1.x; cs[0][dl2 + 5][kl] = vc1.y;
  cs[0][dl2 + 6][kl] = vc1.z; cs[0][dl2 + 7][kl] = vc1.w;

  float acc[2][4] = {{0.f, 0.f, 0.f, 0.f}, {0.f, 0.f, 0.f, 0.f}};

  for (int c = 0; c < 16; c++) {
    int cur = c & 1;
    if (c < 15) {
      int dc = (c + 1) * 32;
      vf = *(const float4*)(frow + dc + dl);
      vc0 = *(const float4*)(crow + dc + dl2);
      vc1 = *(const float4*)(crow + dc + dl2 + 4);
    }
    __syncthreads();
#pragma unroll
    for (int dd = 0; dd < 32; dd++) {
      float2 fv = *(const float2*)&fs[cur][dd][fi];
      float4 cv = *(const float4*)&cs[cur][dd][ki];
      acc[0][0] = fmaf(fv.x, cv.x, acc[0][0]);
      acc[0][1] = fmaf(fv.x, cv.y, acc[0][1]);
      acc[0][2] = fmaf(fv.x, cv.z, acc[0][2]);
      acc[0][3] = fmaf(fv.x, cv.w, acc[0][3]);
      acc[1][0] = fmaf(fv.y, cv.x, acc[1][0]);
      acc[1][1] = fmaf(fv.y, cv.y, acc[1][1]);
      acc[1][2] = fmaf(fv.y, cv.z, acc[1][2]);
      acc[1][3] = fmaf(fv.y, cv.w, acc[1][3]);
    }
    if (c < 15) {
      int nb = cur ^ 1;
      fs[nb][dl + 0][fl] = vf.x; fs[nb][dl + 1][fl] = vf.y;
      fs[nb][dl + 2][fl] = vf.z; fs[nb][dl + 3][fl] = vf.w;
      cs[nb][dl2 + 0][kl] = vc0.x; cs[nb][dl2 + 1][kl] = vc0.y;
      cs[nb][dl2 + 2][kl] = vc0.z; cs[nb][dl2 + 3][kl] = vc0.w;
      cs[nb][dl2 + 4][kl] = vc1.x; cs[nb][dl2 + 5][kl] = vc1.y;
      cs[nb][dl2 + 6][kl] = vc1.z; cs[nb][dl2 + 7][kl] = vc1.w;
    }
  }

#pragma unroll
  for (int u = 0; u < 2; u++) {
    float bv = 1e30f;
    int bi = 0;
#pragma unroll
    for (int j = 0; j < 4; j++) {
      float v = c2v[j] - 2.f * acc[u][j];
      if (v < bv) { bv = v; bi = ki + j; }
    }
    rv[fi + u][kg] = bv;
    ri[fi + u][kg] = bi;
  }
  __syncthreads();
  if (t < 32) {
    float bv = rv[t][0];
    int bi = ri[t][0];
#pragma unroll
    for (int g = 1; g < 16; g++) {
      float v = rv[t][g];
      int i2 = ri[t][g];
      if (v < bv || (v == bv && i2 < bi)) { bv = v; bi = i2; }
    }
    assign[n0 + t] = bi;
    atomicAdd(&counts[bi], 1);
  }
}

// Prefix sums + exact fine-tile worklist (one wave).
__global__ void __launch_bounds__(64) scan_tiles_kernel(
    const int* __restrict__ counts, int* __restrict__ offsets,
    int* __restrict__ tlist, int* __restrict__ ntt) {
  int l = threadIdx.x;
  int c = counts[l];
  int s = c;
#pragma unroll
  for (int o = 1; o < 64; o <<= 1) {
    int v = __shfl_up(s, o);
    if (l >= o) s += v;
  }
  offsets[l] = s - c;
  int nt = (c + TFT - 1) / TFT;
  int s2 = nt;
#pragma unroll
  for (int o = 1; o < 64; o <<= 1) {
    int v = __shfl_up(s2, o);
    if (l >= o) s2 += v;
  }
  int tb = s2 - nt;
  if (l == 63) ntt[0] = s2;
  for (int tt = 0; tt < nt; tt++) tlist[tb + tt] = (l << 16) | tt;
}

__global__ void __launch_bounds__(256) scatter_kernel(
    const int* __restrict__ assign, const int* __restrict__ offsets,
    int* __restrict__ fill, int* __restrict__ order) {
  int n = blockIdx.x * blockDim.x + threadIdx.x;
  int k = assign[n];
  int pos = atomicAdd(&fill[k], 1);
  order[offsets[k] + pos] = n;
}

// Fine distances via bf16 MFMA. Block = worklist tile (32f x 128m), 4 waves,
// wave w owns m-strip [32w,32w+32): 2x2 MFMA 16x16x32 sub-tiles, BK=64,
// double-buffered LDS with XOR 16B-slot swizzle, T14 reg-staged pipeline.
__global__ void __launch_bounds__(256) fine_mfma_kernel(
    const unsigned short* __restrict__ feat_bf,
    const unsigned short* __restrict__ fine_bf,
    const float* __restrict__ f2, const float* __restrict__ p2,
    const int* __restrict__ counts, const int* __restrict__ offsets,
    const int* __restrict__ order, const int* __restrict__ tlist,
    const int* __restrict__ ntt, float* __restrict__ out) {
  int bid = blockIdx.x;
  if (bid >= ntt[0]) return;
  int code = tlist[bid];
  int k = code >> 16;
  int tile = code & 0xffff;
  int nk = counts[k];
  int base = offsets[k];
  int f0 = tile * TFT;
  int nf = min(TFT, nk - f0);

  __shared__ unsigned short Ab[2][32 * 64];    // [buf][row*64 + swz-slot*8]
  __shared__ unsigned short Bb[2][128 * 64];
  __shared__ float red[32][5];

  int t = threadIdx.x;
  int l = t & 63;
  int w = t >> 6;
  int sl8 = l >> 3, sl7 = l & 7;
  int slotw = sl7 ^ sl8;             // swizzled write slot (row&7 == sl8)

  // ---- staging addresses (row stride in LDS = 64 ush = 128 B = 8 x 16B slots)
  int arow = w * 8 + sl8;                                   // 0..31
  int agidx = order[base + f0 + min(arow, nf - 1)];
  const unsigned short* asrc = feat_bf + (size_t)agidx * DIM + sl7 * 8;
  int aoff = arow * 64 + slotw * 8;
  int brow0 = w * 32 + 0 * 8 + sl8;
  int brow1 = w * 32 + 1 * 8 + sl8;
  int brow2 = w * 32 + 2 * 8 + sl8;
  int brow3 = w * 32 + 3 * 8 + sl8;
  const unsigned short* bsrc0 = fine_bf + ((size_t)k * MF + brow0) * DIM + sl7 * 8;
  const unsigned short* bsrc1 = fine_bf + ((size_t)k * MF + brow1) * DIM + sl7 * 8;
  const unsigned short* bsrc2 = fine_bf + ((size_t)k * MF + brow2) * DIM + sl7 * 8;
  const unsigned short* bsrc3 = fine_bf + ((size_t)k * MF + brow3) * DIM + sl7 * 8;
  int boff0 = brow0 * 64 + slotw * 8;
  int boff1 = brow1 * 64 + slotw * 8;
  int boff2 = brow2 * 64 + slotw * 8;
  int boff3 = brow3 * 64 + slotw * 8;

  // ---- fragment read offsets (row&7 == l&7 for both A and B rows)
  int lc = l & 15, lk = l >> 4;
  int sx0 = (lk ^ sl7) * 8;          // ksub=0 slot*8 ; ksub=1 is sx0 ^ 32
  int eA0 = lc * 64, eA1 = (16 + lc) * 64;
  int eB0 = (w * 32 + lc) * 64, eB1 = (w * 32 + 16 + lc) * 64;

  float p2v0 = p2[k * MF + w * 32 + lc];
  float p2v1 = p2[k * MF + w * 32 + 16 + lc];

  f32x4 acc00 = {0.f, 0.f, 0.f, 0.f}, acc01 = acc00, acc10 = acc00, acc11 = acc00;

  // prologue: chunk 0 into buf 0
  uint4 sA = *(const uint4*)asrc;
  uint4 sB0 = *(const uint4*)bsrc0;
  uint4 sB1 = *(const uint4*)bsrc1;
  uint4 sB2 = *(const uint4*)bsrc2;
  uint4 sB3 = *(const uint4*)bsrc3;
  *(uint4*)&Ab[0][aoff] = sA;
  *(uint4*)&Bb[0][boff0] = sB0;
  *(uint4*)&Bb[0][boff1] = sB1;
  *(uint4*)&Bb[0][boff2] = sB2;
  *(uint4*)&Bb[0][boff3] = sB3;
  __syncthreads();

  for (int c = 0; c < NCH; c++) {
    int cur = c & 1;
    if (c + 1 < NCH) {               // issue next-chunk loads early (T14)
      int go = (c + 1) * BKC;
      sA = *(const uint4*)(asrc + go);
      sB0 = *(const uint4*)(bsrc0 + go);
      sB1 = *(const uint4*)(bsrc1 + go);
      sB2 = *(const uint4*)(bsrc2 + go);
      sB3 = *(const uint4*)(bsrc3 + go);
    }
#pragma unroll
    for (int ksub = 0; ksub < 2; ksub++) {
      int sx = sx0 ^ (ksub * 32);
      bf16x8 a0 = *(const bf16x8*)&Ab[cur][eA0 + sx];
      bf16x8 a1 = *(const bf16x8*)&Ab[cur][eA1 + sx];
      bf16x8 b0 = *(const bf16x8*)&Bb[cur][eB0 + sx];
      bf16x8 b1 = *(const bf16x8*)&Bb[cur][eB1 + sx];
      acc00 = __builtin_amdgcn_mfma_f32_16x16x32_bf16(a0, b0, acc00, 0, 0, 0);
      acc01 = __builtin_amdgcn_mfma_f32_16x16x32_bf16(a0, b1, acc01, 0, 0, 0);
      acc10 = __builtin_amdgcn_mfma_f32_16x16x32_bf16(a1, b0, acc10, 0, 0, 0);
      acc11 = __builtin_amdgcn_mfma_f32_16x16x32_bf16(a1, b1, acc11, 0, 0, 0);
    }
    if (c + 1 < NCH) {               // LDS write after compute (latency hidden)
      int nb = cur ^ 1;
      *(uint4*)&Ab[nb][aoff] = sA;
      *(uint4*)&Bb[nb][boff0] = sB0;
      *(uint4*)&Bb[nb][boff1] = sB1;
      *(uint4*)&Bb[nb][boff2] = sB2;
      *(uint4*)&Bb[nb][boff3] = sB3;
    }
    __syncthreads();
  }

  // epilogue: v = min over m of (p2[m] - 2*dot); rows = ft*16 + lk*4 + j
  float v0[4], v1[4];
#pragma unroll
  for (int j = 0; j < 4; j++) {
    v0[j] = fminf(p2v0 - 2.f * acc00[j], p2v1 - 2.f * acc01[j]);
    v1[j] = fminf(p2v0 - 2.f * acc10[j], p2v1 - 2.f * acc11[j]);
  }
#pragma unroll
  for (int mask = 1; mask < 16; mask <<= 1) {
#pragma unroll
    for (int j = 0; j < 4; j++) {
      v0[j] = fminf(v0[j], __shfl_xor(v0[j], mask));
      v1[j] = fminf(v1[j], __shfl_xor(v1[j], mask));
    }
  }
  if (lc == 0) {
#pragma unroll
    for (int j = 0; j < 4; j++) {
      red[lk * 4 + j][w] = v0[j];
      red[16 + lk * 4 + j][w] = v1[j];
    }
  }
  __syncthreads();
  if (t < 64) {
    float val = 0.f;
    if (t < nf) {
      float m = fminf(fminf(red[t][0], red[t][1]), fminf(red[t][2], red[t][3]));
      float d2 = f2[order[base + f0 + t]] + m;
      val = sqrtf(fmaxf(d2, 0.f)) * (1.0f / (float)N_FEAT);
    }
    val = wave_reduce_sum(val);
    if (t == 0) atomicAdd(out, val);
  }
}

extern "C" void kernel_launch(void* const* d_in, const int* in_sizes, int n_in,
                              void* d_out, int out_size, void* d_ws, size_t ws_size,
                              hipStream_t stream) {
  (void)in_sizes; (void)n_in; (void)out_size; (void)ws_size;
  const float* feat   = (const float*)d_in[0];
  const float* coarse = (const float*)d_in[1];
  const float* fine   = (const float*)d_in[2];
  float* out = (float*)d_out;

  unsigned short* feat_bf = (unsigned short*)d_ws;            // 8192*512 (16B-aligned)
  unsigned short* fine_bf = feat_bf + (size_t)N_FEAT * DIM;   // 8192*512
  float* f2      = (float*)(fine_bf + (size_t)KC * MF * DIM); // 8192
  float* c2      = f2 + N_FEAT;             // 64
  float* p2      = c2 + KC;                 // 8192
  int*   assign  = (int*)(p2 + KC * MF);    // 8192
  int*   counts  = assign + N_FEAT;         // 64
  int*   fill    = counts + KC;             // 64
  int*   offsets = fill + KC;               // 64
  int*   order   = offsets + KC;            // 8192
  int*   tlist   = order + N_FEAT;          // 320
  int*   ntt     = tlist + MAXTILES;        // 1

  hipMemsetAsync(out, 0, sizeof(float), stream);
  hipMemsetAsync(counts, 0, 2 * KC * sizeof(int), stream);  // counts + fill

  prep_kernel<<<(N_FEAT + KC + KC * MF) / 4, 256, 0, stream>>>(
      feat, coarse, fine, feat_bf, fine_bf, f2, c2, p2);
  assign_kernel<<<N_FEAT / 32, 256, 0, stream>>>(feat, coarse, c2, assign, counts);
  scan_tiles_kernel<<<1, 64, 0, stream>>>(counts, offsets, tlist, ntt);
  scatter_kernel<<<N_FEAT / 256, 256, 0, stream>>>(assign, offsets, fill, order);
  fine_mfma_kernel<<<MAXTILES, 256, 0, stream>>>(feat_bf, fine_bf, f2, p2, counts,
                                                 offsets, order, tlist, ntt, out);
}

// Round 4
// 89.304 us; speedup vs baseline: 3.8647x; 1.1746x over previous
//
#include <hip/hip_runtime.h>
#include <math.h>
#include <stdint.h>

#define N_FEAT 8192
#define DIM 512
#define KC 64
#define MF 128
#define TFT 32
#define MAXTILES 320   // sum ceil(nk/32) <= 8192/32 + 64 = 320
#define BKC 64         // d-chunk
#define NCH (DIM / BKC)

typedef __attribute__((ext_vector_type(8))) _Float16 f16x8;
typedef __attribute__((ext_vector_type(4))) float f32x4;
typedef unsigned short ush;

__device__ __forceinline__ float wave_reduce_sum(float s) {
#pragma unroll
  for (int o = 32; o; o >>= 1) s += __shfl_xor(s, o);
  return s;
}

// Prep: convert feat/coarse/fine to fp16 (ws), compute f2/c2/p2 norms (exact f32),
// and zero counts/fill/out (block 0) so no hipMemsetAsync dispatches are needed.
__global__ void __launch_bounds__(256) prep_kernel(
    const float* __restrict__ feat, const float* __restrict__ coarse,
    const float* __restrict__ fine, ush* __restrict__ feat_h,
    ush* __restrict__ coarse_h, ush* __restrict__ fine_h,
    float* __restrict__ f2, float* __restrict__ c2, float* __restrict__ p2,
    int* __restrict__ counts, float* __restrict__ out) {
  int t = threadIdx.x;
  if (blockIdx.x == 0) {
    if (t < 2 * KC) counts[t] = 0;   // counts + fill (contiguous)
    if (t == 255) out[0] = 0.f;
  }
  int r = blockIdx.x * 4 + (t >> 6);
  int l = t & 63;
  const float* src;
  ush* dsth;
  float* dstn;
  if (r < N_FEAT) {
    src = feat + (size_t)r * DIM; dsth = feat_h + (size_t)r * DIM; dstn = f2 + r;
  } else if (r < N_FEAT + KC) {
    int rr = r - N_FEAT;
    src = coarse + (size_t)rr * DIM; dsth = coarse_h + (size_t)rr * DIM; dstn = c2 + rr;
  } else {
    int rr = r - N_FEAT - KC;
    src = fine + (size_t)rr * DIM; dsth = fine_h + (size_t)rr * DIM; dstn = p2 + rr;
  }
  float4 a = *(const float4*)(src + l * 8);
  float4 b = *(const float4*)(src + l * 8 + 4);
  float s = a.x * a.x + a.y * a.y + a.z * a.z + a.w * a.w +
            b.x * b.x + b.y * b.y + b.z * b.z + b.w * b.w;
  union { _Float16 h[8]; uint4 v; } o;
  o.h[0] = (_Float16)a.x; o.h[1] = (_Float16)a.y;
  o.h[2] = (_Float16)a.z; o.h[3] = (_Float16)a.w;
  o.h[4] = (_Float16)b.x; o.h[5] = (_Float16)b.y;
  o.h[6] = (_Float16)b.z; o.h[7] = (_Float16)b.w;
  *(uint4*)(dsth + l * 8) = o.v;
  s = wave_reduce_sum(s);
  if (l == 0) *dstn = s;
}

// Coarse assignment via fp16 MFMA: block = 64 features x 64 clusters, 4 waves,
// wave w owns f-strip [16w,16w+16) x all 64 clusters (4 ctiles).
// argmin_k (c2[k] - 2 f.c); norms exact f32, cross-term fp16.
__global__ void __launch_bounds__(256) assign_kernel(
    const ush* __restrict__ feat_h, const ush* __restrict__ coarse_h,
    const float* __restrict__ c2, int* __restrict__ assign,
    int* __restrict__ counts) {
  __shared__ ush Ah[2][64 * 64];
  __shared__ ush Bh[2][64 * 64];

  int t = threadIdx.x;
  int l = t & 63;
  int w = t >> 6;
  int n0 = blockIdx.x * 64;

  // staging: slot = t&7 (16B), rows r0 and r0+32
  int slot = t & 7, r0 = t >> 3;
  int xs = (slot ^ (r0 & 7)) * 8;    // (r0+32)&7 == r0&7
  const ush* a0 = feat_h + (size_t)(n0 + r0) * DIM + slot * 8;
  const ush* a1 = a0 + (size_t)32 * DIM;
  const ush* b0 = coarse_h + (size_t)r0 * DIM + slot * 8;
  const ush* b1 = b0 + (size_t)32 * DIM;
  int offA0 = r0 * 64 + xs, offA1 = (r0 + 32) * 64 + xs;

  // fragment reads
  int lc = l & 15, lk = l >> 4;
  int sx0 = (lk ^ (l & 7)) * 8;
  int eA = (w * 16 + lc) * 64;
  int eB0 = (0 * 16 + lc) * 64, eB1 = (1 * 16 + lc) * 64;
  int eB2 = (2 * 16 + lc) * 64, eB3 = (3 * 16 + lc) * 64;

  f32x4 acc0 = {0.f, 0.f, 0.f, 0.f}, acc1 = acc0, acc2 = acc0, acc3 = acc0;

  uint4 sA0 = *(const uint4*)a0;
  uint4 sA1 = *(const uint4*)a1;
  uint4 sB0 = *(const uint4*)b0;
  uint4 sB1 = *(const uint4*)b1;
  *(uint4*)&Ah[0][offA0] = sA0;
  *(uint4*)&Ah[0][offA1] = sA1;
  *(uint4*)&Bh[0][offA0] = sB0;   // B rows use same (row,slot) mapping
  *(uint4*)&Bh[0][offA1] = sB1;
  __syncthreads();

  for (int c = 0; c < NCH; c++) {
    int cur = c & 1;
    if (c + 1 < NCH) {
      int go = (c + 1) * BKC;
      sA0 = *(const uint4*)(a0 + go);
      sA1 = *(const uint4*)(a1 + go);
      sB0 = *(const uint4*)(b0 + go);
      sB1 = *(const uint4*)(b1 + go);
    }
#pragma unroll
    for (int ksub = 0; ksub < 2; ksub++) {
      int sx = sx0 ^ (ksub * 32);
      f16x8 av = *(const f16x8*)&Ah[cur][eA + sx];
      acc0 = __builtin_amdgcn_mfma_f32_16x16x32_f16(av, *(const f16x8*)&Bh[cur][eB0 + sx], acc0, 0, 0, 0);
      acc1 = __builtin_amdgcn_mfma_f32_16x16x32_f16(av, *(const f16x8*)&Bh[cur][eB1 + sx], acc1, 0, 0, 0);
      acc2 = __builtin_amdgcn_mfma_f32_16x16x32_f16(av, *(const f16x8*)&Bh[cur][eB2 + sx], acc2, 0, 0, 0);
      acc3 = __builtin_amdgcn_mfma_f32_16x16x32_f16(av, *(const f16x8*)&Bh[cur][eB3 + sx], acc3, 0, 0, 0);
    }
    if (c + 1 < NCH) {
      int nb = cur ^ 1;
      *(uint4*)&Ah[nb][offA0] = sA0;
      *(uint4*)&Ah[nb][offA1] = sA1;
      *(uint4*)&Bh[nb][offA0] = sB0;
      *(uint4*)&Bh[nb][offA1] = sB1;
    }
    __syncthreads();
  }

  // epilogue: score = c2[col] - 2*dot; argmin with first-min tiebreak.
  float c2v0 = c2[lc], c2v1 = c2[16 + lc], c2v2 = c2[32 + lc], c2v3 = c2[48 + lc];
#pragma unroll
  for (int j = 0; j < 4; j++) {
    float bv = c2v0 - 2.f * acc0[j];
    int bi = lc;
    float v1 = c2v1 - 2.f * acc1[j];
    if (v1 < bv) { bv = v1; bi = 16 + lc; }
    float v2 = c2v2 - 2.f * acc2[j];
    if (v2 < bv) { bv = v2; bi = 32 + lc; }
    float v3 = c2v3 - 2.f * acc3[j];
    if (v3 < bv) { bv = v3; bi = 48 + lc; }
#pragma unroll
    for (int mask = 1; mask < 16; mask <<= 1) {
      float ov = __shfl_xor(bv, mask);
      int oi = __shfl_xor(bi, mask);
      if (ov < bv || (ov == bv && oi < bi)) { bv = ov; bi = oi; }
    }
    if (lc == 0) {
      int n = n0 + w * 16 + lk * 4 + j;
      assign[n] = bi;
      atomicAdd(&counts[bi], 1);
    }
  }
}

// Prefix sums + exact fine-tile worklist (one wave).
__global__ void __launch_bounds__(64) scan_tiles_kernel(
    const int* __restrict__ counts, int* __restrict__ offsets,
    int* __restrict__ tlist, int* __restrict__ ntt) {
  int l = threadIdx.x;
  int c = counts[l];
  int s = c;
#pragma unroll
  for (int o = 1; o < 64; o <<= 1) {
    int v = __shfl_up(s, o);
    if (l >= o) s += v;
  }
  offsets[l] = s - c;
  int nt = (c + TFT - 1) / TFT;
  int s2 = nt;
#pragma unroll
  for (int o = 1; o < 64; o <<= 1) {
    int v = __shfl_up(s2, o);
    if (l >= o) s2 += v;
  }
  int tb = s2 - nt;
  if (l == 63) ntt[0] = s2;
  for (int tt = 0; tt < nt; tt++) tlist[tb + tt] = (l << 16) | tt;
}

__global__ void __launch_bounds__(256) scatter_kernel(
    const int* __restrict__ assign, const int* __restrict__ offsets,
    int* __restrict__ fill, int* __restrict__ order) {
  int n = blockIdx.x * blockDim.x + threadIdx.x;
  int k = assign[n];
  int pos = atomicAdd(&fill[k], 1);
  order[offsets[k] + pos] = n;
}

// Fine distances via fp16 MFMA. Block = worklist tile (32f x 128m), 4 waves,
// wave w owns m-strip [32w,32w+32): 2x2 MFMA 16x16x32 sub-tiles, BK=64,
// double-buffered LDS with XOR 16B-slot swizzle, reg-staged pipeline.
__global__ void __launch_bounds__(256) fine_mfma_kernel(
    const ush* __restrict__ feat_h, const ush* __restrict__ fine_h,
    const float* __restrict__ f2, const float* __restrict__ p2,
    const int* __restrict__ counts, const int* __restrict__ offsets,
    const int* __restrict__ order, const int* __restrict__ tlist,
    const int* __restrict__ ntt, float* __restrict__ out) {
  int bid = blockIdx.x;
  if (bid >= ntt[0]) return;
  int code = tlist[bid];
  int k = code >> 16;
  int tile = code & 0xffff;
  int nk = counts[k];
  int base = offsets[k];
  int f0 = tile * TFT;
  int nf = min(TFT, nk - f0);

  __shared__ ush Ab[2][32 * 64];
  __shared__ ush Bb[2][128 * 64];
  __shared__ float red[32][5];

  int t = threadIdx.x;
  int l = t & 63;
  int w = t >> 6;
  int sl8 = l >> 3, sl7 = l & 7;
  int slotw = sl7 ^ sl8;

  int arow = w * 8 + sl8;
  int agidx = order[base + f0 + min(arow, nf - 1)];
  const ush* asrc = feat_h + (size_t)agidx * DIM + sl7 * 8;
  int aoff = arow * 64 + slotw * 8;
  int brow0 = w * 32 + 0 * 8 + sl8;
  int brow1 = w * 32 + 1 * 8 + sl8;
  int brow2 = w * 32 + 2 * 8 + sl8;
  int brow3 = w * 32 + 3 * 8 + sl8;
  const ush* bsrc0 = fine_h + ((size_t)k * MF + brow0) * DIM + sl7 * 8;
  const ush* bsrc1 = fine_h + ((size_t)k * MF + brow1) * DIM + sl7 * 8;
  const ush* bsrc2 = fine_h + ((size_t)k * MF + brow2) * DIM + sl7 * 8;
  const ush* bsrc3 = fine_h + ((size_t)k * MF + brow3) * DIM + sl7 * 8;
  int boff0 = brow0 * 64 + slotw * 8;
  int boff1 = brow1 * 64 + slotw * 8;
  int boff2 = brow2 * 64 + slotw * 8;
  int boff3 = brow3 * 64 + slotw * 8;

  int lc = l & 15, lk = l >> 4;
  int sx0 = (lk ^ sl7) * 8;
  int eA0 = lc * 64, eA1 = (16 + lc) * 64;
  int eB0 = (w * 32 + lc) * 64, eB1 = (w * 32 + 16 + lc) * 64;

  float p2v0 = p2[k * MF + w * 32 + lc];
  float p2v1 = p2[k * MF + w * 32 + 16 + lc];

  f32x4 acc00 = {0.f, 0.f, 0.f, 0.f}, acc01 = acc00, acc10 = acc00, acc11 = acc00;

  uint4 sA = *(const uint4*)asrc;
  uint4 sB0 = *(const uint4*)bsrc0;
  uint4 sB1 = *(const uint4*)bsrc1;
  uint4 sB2 = *(const uint4*)bsrc2;
  uint4 sB3 = *(const uint4*)bsrc3;
  *(uint4*)&Ab[0][aoff] = sA;
  *(uint4*)&Bb[0][boff0] = sB0;
  *(uint4*)&Bb[0][boff1] = sB1;
  *(uint4*)&Bb[0][boff2] = sB2;
  *(uint4*)&Bb[0][boff3] = sB3;
  __syncthreads();

  for (int c = 0; c < NCH; c++) {
    int cur = c & 1;
    if (c + 1 < NCH) {
      int go = (c + 1) * BKC;
      sA = *(const uint4*)(asrc + go);
      sB0 = *(const uint4*)(bsrc0 + go);
      sB1 = *(const uint4*)(bsrc1 + go);
      sB2 = *(const uint4*)(bsrc2 + go);
      sB3 = *(const uint4*)(bsrc3 + go);
    }
#pragma unroll
    for (int ksub = 0; ksub < 2; ksub++) {
      int sx = sx0 ^ (ksub * 32);
      f16x8 a0 = *(const f16x8*)&Ab[cur][eA0 + sx];
      f16x8 a1 = *(const f16x8*)&Ab[cur][eA1 + sx];
      f16x8 b0 = *(const f16x8*)&Bb[cur][eB0 + sx];
      f16x8 b1 = *(const f16x8*)&Bb[cur][eB1 + sx];
      acc00 = __builtin_amdgcn_mfma_f32_16x16x32_f16(a0, b0, acc00, 0, 0, 0);
      acc01 = __builtin_amdgcn_mfma_f32_16x16x32_f16(a0, b1, acc01, 0, 0, 0);
      acc10 = __builtin_amdgcn_mfma_f32_16x16x32_f16(a1, b0, acc10, 0, 0, 0);
      acc11 = __builtin_amdgcn_mfma_f32_16x16x32_f16(a1, b1, acc11, 0, 0, 0);
    }
    if (c + 1 < NCH) {
      int nb = cur ^ 1;
      *(uint4*)&Ab[nb][aoff] = sA;
      *(uint4*)&Bb[nb][boff0] = sB0;
      *(uint4*)&Bb[nb][boff1] = sB1;
      *(uint4*)&Bb[nb][boff2] = sB2;
      *(uint4*)&Bb[nb][boff3] = sB3;
    }
    __syncthreads();
  }

  float v0[4], v1[4];
#pragma unroll
  for (int j = 0; j < 4; j++) {
    v0[j] = fminf(p2v0 - 2.f * acc00[j], p2v1 - 2.f * acc01[j]);
    v1[j] = fminf(p2v0 - 2.f * acc10[j], p2v1 - 2.f * acc11[j]);
  }
#pragma unroll
  for (int mask = 1; mask < 16; mask <<= 1) {
#pragma unroll
    for (int j = 0; j < 4; j++) {
      v0[j] = fminf(v0[j], __shfl_xor(v0[j], mask));
      v1[j] = fminf(v1[j], __shfl_xor(v1[j], mask));
    }
  }
  if (lc == 0) {
#pragma unroll
    for (int j = 0; j < 4; j++) {
      red[lk * 4 + j][w] = v0[j];
      red[16 + lk * 4 + j][w] = v1[j];
    }
  }
  __syncthreads();
  if (t < 64) {
    float val = 0.f;
    if (t < nf) {
      float m = fminf(fminf(red[t][0], red[t][1]), fminf(red[t][2], red[t][3]));
      float d2 = f2[order[base + f0 + t]] + m;
      val = sqrtf(fmaxf(d2, 0.f)) * (1.0f / (float)N_FEAT);
    }
    val = wave_reduce_sum(val);
    if (t == 0) atomicAdd(out, val);
  }
}

extern "C" void kernel_launch(void* const* d_in, const int* in_sizes, int n_in,
                              void* d_out, int out_size, void* d_ws, size_t ws_size,
                              hipStream_t stream) {
  (void)in_sizes; (void)n_in; (void)out_size; (void)ws_size;
  const float* feat   = (const float*)d_in[0];
  const float* coarse = (const float*)d_in[1];
  const float* fine   = (const float*)d_in[2];
  float* out = (float*)d_out;

  ush* feat_h   = (ush*)d_ws;                          // 8192*512
  ush* fine_h   = feat_h + (size_t)N_FEAT * DIM;       // 8192*512
  ush* coarse_h = fine_h + (size_t)KC * MF * DIM;      // 64*512
  float* f2     = (float*)(coarse_h + (size_t)KC * DIM);  // 8192
  float* c2     = f2 + N_FEAT;              // 64
  float* p2     = c2 + KC;                  // 8192
  int* assign   = (int*)(p2 + KC * MF);     // 8192
  int* counts   = assign + N_FEAT;          // 64
  int* fill     = counts + KC;              // 64 (contiguous with counts)
  int* offsets  = fill + KC;                // 64
  int* order    = offsets + KC;             // 8192
  int* tlist    = order + N_FEAT;           // 320
  int* ntt      = tlist + MAXTILES;         // 1

  prep_kernel<<<(N_FEAT + KC + KC * MF) / 4, 256, 0, stream>>>(
      feat, coarse, fine, feat_h, coarse_h, fine_h, f2, c2, p2, counts, out);
  assign_kernel<<<N_FEAT / 64, 256, 0, stream>>>(feat_h, coarse_h, c2, assign, counts);
  scan_tiles_kernel<<<1, 64, 0, stream>>>(counts, offsets, tlist, ntt);
  scatter_kernel<<<N_FEAT / 256, 256, 0, stream>>>(assign, offsets, fill, order);
  fine_mfma_kernel<<<MAXTILES, 256, 0, stream>>>(feat_h, fine_h, f2, p2, counts,
                                                 offsets, order, tlist, ntt, out);
}

// Round 5
// 62.267 us; speedup vs baseline: 5.5428x; 1.4342x over previous
//
#include <hip/hip_runtime.h>
#include <math.h>
#include <stdint.h>

#define N_FEAT 8192
#define DIM 512
#define KC 64
#define MF 128
#define TFT 32
#define MAXTILES 320   // max sum ceil(nk/32) over 64 clusters, sum nk = 8192
#define BKC 64         // d-chunk
#define NCH (DIM / BKC)

typedef __attribute__((ext_vector_type(8))) _Float16 f16x8;
typedef __attribute__((ext_vector_type(4))) float f32x4;
typedef unsigned short ush;

__device__ __forceinline__ float wave_reduce_sum(float s) {
#pragma unroll
  for (int o = 32; o; o >>= 1) s += __shfl_xor(s, o);
  return s;
}

// Prep: convert feat/coarse/fine to fp16 (ws), compute f2/c2/p2 norms (exact f32),
// and zero counts/out (block 0) so no fill dispatches are needed.
__global__ void __launch_bounds__(256) prep_kernel(
    const float* __restrict__ feat, const float* __restrict__ coarse,
    const float* __restrict__ fine, ush* __restrict__ feat_h,
    ush* __restrict__ coarse_h, ush* __restrict__ fine_h,
    float* __restrict__ f2, float* __restrict__ c2, float* __restrict__ p2,
    int* __restrict__ counts, float* __restrict__ out) {
  int t = threadIdx.x;
  if (blockIdx.x == 0) {
    if (t < KC) counts[t] = 0;
    if (t == 255) out[0] = 0.f;
  }
  int r = blockIdx.x * 4 + (t >> 6);
  int l = t & 63;
  const float* src;
  ush* dsth;
  float* dstn;
  if (r < N_FEAT) {
    src = feat + (size_t)r * DIM; dsth = feat_h + (size_t)r * DIM; dstn = f2 + r;
  } else if (r < N_FEAT + KC) {
    int rr = r - N_FEAT;
    src = coarse + (size_t)rr * DIM; dsth = coarse_h + (size_t)rr * DIM; dstn = c2 + rr;
  } else {
    int rr = r - N_FEAT - KC;
    src = fine + (size_t)rr * DIM; dsth = fine_h + (size_t)rr * DIM; dstn = p2 + rr;
  }
  float4 a = *(const float4*)(src + l * 8);
  float4 b = *(const float4*)(src + l * 8 + 4);
  float s = a.x * a.x + a.y * a.y + a.z * a.z + a.w * a.w +
            b.x * b.x + b.y * b.y + b.z * b.z + b.w * b.w;
  union { _Float16 h[8]; uint4 v; } o;
  o.h[0] = (_Float16)a.x; o.h[1] = (_Float16)a.y;
  o.h[2] = (_Float16)a.z; o.h[3] = (_Float16)a.w;
  o.h[4] = (_Float16)b.x; o.h[5] = (_Float16)b.y;
  o.h[6] = (_Float16)b.z; o.h[7] = (_Float16)b.w;
  *(uint4*)(dsth + l * 8) = o.v;
  s = wave_reduce_sum(s);
  if (l == 0) *dstn = s;
}

// Coarse assignment via fp16 MFMA, fused direct scatter: block = 64f x 64c,
// 4 waves; wave w owns f-strip [16w,16w+16). argmin_k (c2[k] - 2 f.c), then
// order[k][atomicAdd(counts[k])] = n  (fixed 8192-capacity buckets).
__global__ void __launch_bounds__(256) assign_kernel(
    const ush* __restrict__ feat_h, const ush* __restrict__ coarse_h,
    const float* __restrict__ c2, int* __restrict__ counts,
    int* __restrict__ order) {
  __shared__ ush Ah[2][64 * 64];
  __shared__ ush Bh[2][64 * 64];

  int t = threadIdx.x;
  int l = t & 63;
  int w = t >> 6;
  int n0 = blockIdx.x * 64;

  // staging: slot = t&7 (16B), rows r0 and r0+32
  int slot = t & 7, r0 = t >> 3;
  int xs = (slot ^ (r0 & 7)) * 8;    // (r0+32)&7 == r0&7
  const ush* a0 = feat_h + (size_t)(n0 + r0) * DIM + slot * 8;
  const ush* a1 = a0 + (size_t)32 * DIM;
  const ush* b0 = coarse_h + (size_t)r0 * DIM + slot * 8;
  const ush* b1 = b0 + (size_t)32 * DIM;
  int offA0 = r0 * 64 + xs, offA1 = (r0 + 32) * 64 + xs;

  // fragment reads
  int lc = l & 15, lk = l >> 4;
  int sx0 = (lk ^ (l & 7)) * 8;
  int eA = (w * 16 + lc) * 64;
  int eB0 = (0 * 16 + lc) * 64, eB1 = (1 * 16 + lc) * 64;
  int eB2 = (2 * 16 + lc) * 64, eB3 = (3 * 16 + lc) * 64;

  f32x4 acc0 = {0.f, 0.f, 0.f, 0.f}, acc1 = acc0, acc2 = acc0, acc3 = acc0;

  uint4 sA0 = *(const uint4*)a0;
  uint4 sA1 = *(const uint4*)a1;
  uint4 sB0 = *(const uint4*)b0;
  uint4 sB1 = *(const uint4*)b1;
  *(uint4*)&Ah[0][offA0] = sA0;
  *(uint4*)&Ah[0][offA1] = sA1;
  *(uint4*)&Bh[0][offA0] = sB0;
  *(uint4*)&Bh[0][offA1] = sB1;
  __syncthreads();

  for (int c = 0; c < NCH; c++) {
    int cur = c & 1;
    if (c + 1 < NCH) {
      int go = (c + 1) * BKC;
      sA0 = *(const uint4*)(a0 + go);
      sA1 = *(const uint4*)(a1 + go);
      sB0 = *(const uint4*)(b0 + go);
      sB1 = *(const uint4*)(b1 + go);
    }
#pragma unroll
    for (int ksub = 0; ksub < 2; ksub++) {
      int sx = sx0 ^ (ksub * 32);
      f16x8 av = *(const f16x8*)&Ah[cur][eA + sx];
      acc0 = __builtin_amdgcn_mfma_f32_16x16x32_f16(av, *(const f16x8*)&Bh[cur][eB0 + sx], acc0, 0, 0, 0);
      acc1 = __builtin_amdgcn_mfma_f32_16x16x32_f16(av, *(const f16x8*)&Bh[cur][eB1 + sx], acc1, 0, 0, 0);
      acc2 = __builtin_amdgcn_mfma_f32_16x16x32_f16(av, *(const f16x8*)&Bh[cur][eB2 + sx], acc2, 0, 0, 0);
      acc3 = __builtin_amdgcn_mfma_f32_16x16x32_f16(av, *(const f16x8*)&Bh[cur][eB3 + sx], acc3, 0, 0, 0);
    }
    if (c + 1 < NCH) {
      int nb = cur ^ 1;
      *(uint4*)&Ah[nb][offA0] = sA0;
      *(uint4*)&Ah[nb][offA1] = sA1;
      *(uint4*)&Bh[nb][offA0] = sB0;
      *(uint4*)&Bh[nb][offA1] = sB1;
    }
    __syncthreads();
  }

  // epilogue: score = c2[col] - 2*dot; argmin (first-min tiebreak); scatter.
  float c2v0 = c2[lc], c2v1 = c2[16 + lc], c2v2 = c2[32 + lc], c2v3 = c2[48 + lc];
#pragma unroll
  for (int j = 0; j < 4; j++) {
    float bv = c2v0 - 2.f * acc0[j];
    int bi = lc;
    float v1 = c2v1 - 2.f * acc1[j];
    if (v1 < bv) { bv = v1; bi = 16 + lc; }
    float v2 = c2v2 - 2.f * acc2[j];
    if (v2 < bv) { bv = v2; bi = 32 + lc; }
    float v3 = c2v3 - 2.f * acc3[j];
    if (v3 < bv) { bv = v3; bi = 48 + lc; }
#pragma unroll
    for (int mask = 1; mask < 16; mask <<= 1) {
      float ov = __shfl_xor(bv, mask);
      int oi = __shfl_xor(bi, mask);
      if (ov < bv || (ov == bv && oi < bi)) { bv = ov; bi = oi; }
    }
    if (lc == 0) {
      int n = n0 + w * 16 + lk * 4 + j;
      int pos = atomicAdd(&counts[bi], 1);
      order[bi * N_FEAT + pos] = n;
    }
  }
}

// Fine distances via fp16 MFMA. Self-scheduling: each block scans counts[] to
// find its (cluster k, tile) pair. Tile = 32f x 128m, 4 waves, 2x2 MFMA
// 16x16x32 sub-tiles, BK=64 double-buffered swizzled LDS, reg-staged pipeline.
__global__ void __launch_bounds__(256) fine_mfma_kernel(
    const ush* __restrict__ feat_h, const ush* __restrict__ fine_h,
    const float* __restrict__ f2, const float* __restrict__ p2,
    const int* __restrict__ counts, const int* __restrict__ order,
    float* __restrict__ out) {
  __shared__ int meta[3];   // k, tile, total
  int t = threadIdx.x;
  int bid = blockIdx.x;
  if (t < 64) {
    int c = counts[t];
    int nt = (c + TFT - 1) / TFT;
    int s2 = nt;
#pragma unroll
    for (int o = 1; o < 64; o <<= 1) {
      int v = __shfl_up(s2, o);
      if (t >= o) s2 += v;
    }
    int tb = s2 - nt;
    if (t == 63) meta[2] = s2;
    if (bid >= tb && bid < tb + nt) { meta[0] = t; meta[1] = bid - tb; }
  }
  __syncthreads();
  if (bid >= meta[2]) return;
  int k = meta[0];
  int tile = meta[1];
  int nk = counts[k];
  int base = k * N_FEAT;
  int f0 = tile * TFT;
  int nf = min(TFT, nk - f0);

  __shared__ ush Ab[2][32 * 64];
  __shared__ ush Bb[2][128 * 64];
  __shared__ float red[32][5];

  int l = t & 63;
  int w = t >> 6;
  int sl8 = l >> 3, sl7 = l & 7;
  int slotw = sl7 ^ sl8;

  int arow = w * 8 + sl8;
  int agidx = order[base + f0 + min(arow, nf - 1)];
  const ush* asrc = feat_h + (size_t)agidx * DIM + sl7 * 8;
  int aoff = arow * 64 + slotw * 8;
  int brow0 = w * 32 + 0 * 8 + sl8;
  int brow1 = w * 32 + 1 * 8 + sl8;
  int brow2 = w * 32 + 2 * 8 + sl8;
  int brow3 = w * 32 + 3 * 8 + sl8;
  const ush* bsrc0 = fine_h + ((size_t)k * MF + brow0) * DIM + sl7 * 8;
  const ush* bsrc1 = fine_h + ((size_t)k * MF + brow1) * DIM + sl7 * 8;
  const ush* bsrc2 = fine_h + ((size_t)k * MF + brow2) * DIM + sl7 * 8;
  const ush* bsrc3 = fine_h + ((size_t)k * MF + brow3) * DIM + sl7 * 8;
  int boff0 = brow0 * 64 + slotw * 8;
  int boff1 = brow1 * 64 + slotw * 8;
  int boff2 = brow2 * 64 + slotw * 8;
  int boff3 = brow3 * 64 + slotw * 8;

  int lc = l & 15, lk = l >> 4;
  int sx0 = (lk ^ sl7) * 8;
  int eA0 = lc * 64, eA1 = (16 + lc) * 64;
  int eB0 = (w * 32 + lc) * 64, eB1 = (w * 32 + 16 + lc) * 64;

  float p2v0 = p2[k * MF + w * 32 + lc];
  float p2v1 = p2[k * MF + w * 32 + 16 + lc];

  f32x4 acc00 = {0.f, 0.f, 0.f, 0.f}, acc01 = acc00, acc10 = acc00, acc11 = acc00;

  uint4 sA = *(const uint4*)asrc;
  uint4 sB0 = *(const uint4*)bsrc0;
  uint4 sB1 = *(const uint4*)bsrc1;
  uint4 sB2 = *(const uint4*)bsrc2;
  uint4 sB3 = *(const uint4*)bsrc3;
  *(uint4*)&Ab[0][aoff] = sA;
  *(uint4*)&Bb[0][boff0] = sB0;
  *(uint4*)&Bb[0][boff1] = sB1;
  *(uint4*)&Bb[0][boff2] = sB2;
  *(uint4*)&Bb[0][boff3] = sB3;
  __syncthreads();

  for (int c = 0; c < NCH; c++) {
    int cur = c & 1;
    if (c + 1 < NCH) {
      int go = (c + 1) * BKC;
      sA = *(const uint4*)(asrc + go);
      sB0 = *(const uint4*)(bsrc0 + go);
      sB1 = *(const uint4*)(bsrc1 + go);
      sB2 = *(const uint4*)(bsrc2 + go);
      sB3 = *(const uint4*)(bsrc3 + go);
    }
#pragma unroll
    for (int ksub = 0; ksub < 2; ksub++) {
      int sx = sx0 ^ (ksub * 32);
      f16x8 a0 = *(const f16x8*)&Ab[cur][eA0 + sx];
      f16x8 a1 = *(const f16x8*)&Ab[cur][eA1 + sx];
      f16x8 b0 = *(const f16x8*)&Bb[cur][eB0 + sx];
      f16x8 b1 = *(const f16x8*)&Bb[cur][eB1 + sx];
      acc00 = __builtin_amdgcn_mfma_f32_16x16x32_f16(a0, b0, acc00, 0, 0, 0);
      acc01 = __builtin_amdgcn_mfma_f32_16x16x32_f16(a0, b1, acc01, 0, 0, 0);
      acc10 = __builtin_amdgcn_mfma_f32_16x16x32_f16(a1, b0, acc10, 0, 0, 0);
      acc11 = __builtin_amdgcn_mfma_f32_16x16x32_f16(a1, b1, acc11, 0, 0, 0);
    }
    if (c + 1 < NCH) {
      int nb = cur ^ 1;
      *(uint4*)&Ab[nb][aoff] = sA;
      *(uint4*)&Bb[nb][boff0] = sB0;
      *(uint4*)&Bb[nb][boff1] = sB1;
      *(uint4*)&Bb[nb][boff2] = sB2;
      *(uint4*)&Bb[nb][boff3] = sB3;
    }
    __syncthreads();
  }

  float v0[4], v1[4];
#pragma unroll
  for (int j = 0; j < 4; j++) {
    v0[j] = fminf(p2v0 - 2.f * acc00[j], p2v1 - 2.f * acc01[j]);
    v1[j] = fminf(p2v0 - 2.f * acc10[j], p2v1 - 2.f * acc11[j]);
  }
#pragma unroll
  for (int mask = 1; mask < 16; mask <<= 1) {
#pragma unroll
    for (int j = 0; j < 4; j++) {
      v0[j] = fminf(v0[j], __shfl_xor(v0[j], mask));
      v1[j] = fminf(v1[j], __shfl_xor(v1[j], mask));
    }
  }
  if (lc == 0) {
#pragma unroll
    for (int j = 0; j < 4; j++) {
      red[lk * 4 + j][w] = v0[j];
      red[16 + lk * 4 + j][w] = v1[j];
    }
  }
  __syncthreads();
  if (t < 64) {
    float val = 0.f;
    if (t < nf) {
      float m = fminf(fminf(red[t][0], red[t][1]), fminf(red[t][2], red[t][3]));
      float d2 = f2[order[base + f0 + t]] + m;
      val = sqrtf(fmaxf(d2, 0.f)) * (1.0f / (float)N_FEAT);
    }
    val = wave_reduce_sum(val);
    if (t == 0) atomicAdd(out, val);
  }
}

extern "C" void kernel_launch(void* const* d_in, const int* in_sizes, int n_in,
                              void* d_out, int out_size, void* d_ws, size_t ws_size,
                              hipStream_t stream) {
  (void)in_sizes; (void)n_in; (void)out_size; (void)ws_size;
  const float* feat   = (const float*)d_in[0];
  const float* coarse = (const float*)d_in[1];
  const float* fine   = (const float*)d_in[2];
  float* out = (float*)d_out;

  ush* feat_h   = (ush*)d_ws;                          // 8192*512
  ush* fine_h   = feat_h + (size_t)N_FEAT * DIM;       // 8192*512
  ush* coarse_h = fine_h + (size_t)KC * MF * DIM;      // 64*512
  float* f2     = (float*)(coarse_h + (size_t)KC * DIM);  // 8192
  float* c2     = f2 + N_FEAT;              // 64
  float* p2     = c2 + KC;                  // 8192
  int* counts   = (int*)(p2 + KC * MF);     // 64
  int* order    = counts + KC;              // 64 * 8192 (fixed-capacity buckets)

  prep_kernel<<<(N_FEAT + KC + KC * MF) / 4, 256, 0, stream>>>(
      feat, coarse, fine, feat_h, coarse_h, fine_h, f2, c2, p2, counts, out);
  assign_kernel<<<N_FEAT / 64, 256, 0, stream>>>(feat_h, coarse_h, c2, counts, order);
  fine_mfma_kernel<<<MAXTILES, 256, 0, stream>>>(feat_h, fine_h, f2, p2, counts,
                                                 order, out);
}

// Round 6
// 39.697 us; speedup vs baseline: 8.6943x; 1.5686x over previous
//
#include <hip/hip_runtime.h>
#include <math.h>
#include <stdint.h>

#define N_FEAT 8192
#define DIM 512
#define KC 64
#define MF 128
#define TFT 32
#define MAXTILES 320   // max sum ceil(nk/32), sum nk = 8192
#define BKC 64         // d-chunk
#define NCH (DIM / BKC)

typedef __attribute__((ext_vector_type(8))) _Float16 f16x8;
typedef __attribute__((ext_vector_type(4))) float f32x4;
typedef unsigned short ush;

__device__ __forceinline__ float wave_reduce_sum(float s) {
#pragma unroll
  for (int o = 32; o; o >>= 1) s += __shfl_xor(s, o);
  return s;
}

// convert 8 f32 -> 8 fp16 (RTNE) packed in uint4; accumulate exact f32 sq-sum
__device__ __forceinline__ uint4 cvt8(float4 a, float4 b, float& sq) {
  sq = fmaf(a.x, a.x, sq); sq = fmaf(a.y, a.y, sq);
  sq = fmaf(a.z, a.z, sq); sq = fmaf(a.w, a.w, sq);
  sq = fmaf(b.x, b.x, sq); sq = fmaf(b.y, b.y, sq);
  sq = fmaf(b.z, b.z, sq); sq = fmaf(b.w, b.w, sq);
  union { _Float16 h[8]; uint4 v; } o;
  o.h[0] = (_Float16)a.x; o.h[1] = (_Float16)a.y;
  o.h[2] = (_Float16)a.z; o.h[3] = (_Float16)a.w;
  o.h[4] = (_Float16)b.x; o.h[5] = (_Float16)b.y;
  o.h[6] = (_Float16)b.z; o.h[7] = (_Float16)b.w;
  return o.v;
}

// Node 1: blocks 0..127 = coarse assignment (fp16 MFMA) fused with feature
// conversion + f2 norms + in-block c2; blocks 128..255 = fine-prototype
// conversion + p2 norms. No atomics; assignment written as a plain array.
__global__ void __launch_bounds__(256) fused_prep_assign_kernel(
    const float* __restrict__ feat, const float* __restrict__ coarse,
    const float* __restrict__ fine, ush* __restrict__ feat_h,
    ush* __restrict__ fine_h, float* __restrict__ f2, float* __restrict__ p2,
    int* __restrict__ assign, float* __restrict__ out) {
  __shared__ ush Ah[2][64 * 64];
  __shared__ ush Bh[2][64 * 64];
  __shared__ float c2s[64];

  int t = threadIdx.x;
  int bid = blockIdx.x;

  if (bid >= 128) {            // ---- converter blocks: fine -> fp16, p2 norms
    int cb = bid - 128;
    int l = t & 63;
#pragma unroll 4
    for (int i = 0; i < 16; i++) {
      int r = cb * 4 + (t >> 6) + i * 512;
      const float* src = fine + (size_t)r * DIM + l * 8;
      float4 a = *(const float4*)src;
      float4 b = *(const float4*)(src + 4);
      float s = 0.f;
      uint4 h = cvt8(a, b, s);
      *(uint4*)(fine_h + (size_t)r * DIM + l * 8) = h;
      s = wave_reduce_sum(s);
      if (l == 0) p2[r] = s;
    }
    return;
  }

  if (bid == 0 && t == 0) out[0] = 0.f;

  int l = t & 63, w = t >> 6;
  int n0 = bid * 64;
  int slot = t & 7, r0 = t >> 3;           // staging row 0..31 (+32 pair)
  int xs = (slot ^ (r0 & 7)) * 8;          // XOR 16B-slot swizzle
  const float* a0 = feat + (size_t)(n0 + r0) * DIM + slot * 8;
  const float* a1 = a0 + (size_t)32 * DIM;
  const float* b0 = coarse + (size_t)r0 * DIM + slot * 8;
  const float* b1 = b0 + (size_t)32 * DIM;
  ush* fh0 = feat_h + (size_t)(n0 + r0) * DIM + slot * 8;
  ush* fh1 = fh0 + (size_t)32 * DIM;
  int offA0 = r0 * 64 + xs, offA1 = (r0 + 32) * 64 + xs;

  int lc = l & 15, lk = l >> 4;
  int sx0 = (lk ^ (l & 7)) * 8;
  int eA = (w * 16 + lc) * 64;
  int eB0 = lc * 64, eB1 = (16 + lc) * 64, eB2 = (32 + lc) * 64, eB3 = (48 + lc) * 64;

  float sa0 = 0.f, sa1 = 0.f, sb0 = 0.f, sb1 = 0.f;
  f32x4 acc0 = {0.f, 0.f, 0.f, 0.f}, acc1 = acc0, acc2 = acc0, acc3 = acc0;

  // prologue: chunk 0
  float4 va0a = *(const float4*)a0, va0b = *(const float4*)(a0 + 4);
  float4 va1a = *(const float4*)a1, va1b = *(const float4*)(a1 + 4);
  float4 vb0a = *(const float4*)b0, vb0b = *(const float4*)(b0 + 4);
  float4 vb1a = *(const float4*)b1, vb1b = *(const float4*)(b1 + 4);
  {
    uint4 hA0 = cvt8(va0a, va0b, sa0);
    uint4 hA1 = cvt8(va1a, va1b, sa1);
    uint4 hB0 = cvt8(vb0a, vb0b, sb0);
    uint4 hB1 = cvt8(vb1a, vb1b, sb1);
    *(uint4*)&Ah[0][offA0] = hA0; *(uint4*)&Ah[0][offA1] = hA1;
    *(uint4*)&Bh[0][offA0] = hB0; *(uint4*)&Bh[0][offA1] = hB1;
    *(uint4*)fh0 = hA0; *(uint4*)fh1 = hA1;
  }
  __syncthreads();

  for (int c = 0; c < NCH; c++) {
    int cur = c & 1;
    if (c + 1 < NCH) {                     // issue next-chunk loads early
      int go = (c + 1) * BKC;
      va0a = *(const float4*)(a0 + go); va0b = *(const float4*)(a0 + go + 4);
      va1a = *(const float4*)(a1 + go); va1b = *(const float4*)(a1 + go + 4);
      vb0a = *(const float4*)(b0 + go); vb0b = *(const float4*)(b0 + go + 4);
      vb1a = *(const float4*)(b1 + go); vb1b = *(const float4*)(b1 + go + 4);
    }
#pragma unroll
    for (int ksub = 0; ksub < 2; ksub++) {
      int sx = sx0 ^ (ksub * 32);
      f16x8 av = *(const f16x8*)&Ah[cur][eA + sx];
      acc0 = __builtin_amdgcn_mfma_f32_16x16x32_f16(av, *(const f16x8*)&Bh[cur][eB0 + sx], acc0, 0, 0, 0);
      acc1 = __builtin_amdgcn_mfma_f32_16x16x32_f16(av, *(const f16x8*)&Bh[cur][eB1 + sx], acc1, 0, 0, 0);
      acc2 = __builtin_amdgcn_mfma_f32_16x16x32_f16(av, *(const f16x8*)&Bh[cur][eB2 + sx], acc2, 0, 0, 0);
      acc3 = __builtin_amdgcn_mfma_f32_16x16x32_f16(av, *(const f16x8*)&Bh[cur][eB3 + sx], acc3, 0, 0, 0);
    }
    if (c + 1 < NCH) {                     // convert + write after MFMA
      int go = (c + 1) * BKC;
      int nb = cur ^ 1;
      uint4 hA0 = cvt8(va0a, va0b, sa0);
      uint4 hA1 = cvt8(va1a, va1b, sa1);
      uint4 hB0 = cvt8(vb0a, vb0b, sb0);
      uint4 hB1 = cvt8(vb1a, vb1b, sb1);
      *(uint4*)&Ah[nb][offA0] = hA0; *(uint4*)&Ah[nb][offA1] = hA1;
      *(uint4*)&Bh[nb][offA0] = hB0; *(uint4*)&Bh[nb][offA1] = hB1;
      *(uint4*)(fh0 + go) = hA0; *(uint4*)(fh1 + go) = hA1;
    }
    __syncthreads();
  }

  // reduce norms across the 8 slot-lanes of each staging row
#pragma unroll
  for (int m = 1; m < 8; m <<= 1) {
    sa0 += __shfl_xor(sa0, m); sa1 += __shfl_xor(sa1, m);
    sb0 += __shfl_xor(sb0, m); sb1 += __shfl_xor(sb1, m);
  }
  if (slot == 0) {
    f2[n0 + r0] = sa0; f2[n0 + r0 + 32] = sa1;
    c2s[r0] = sb0;     c2s[r0 + 32] = sb1;
  }
  __syncthreads();

  // epilogue: score = c2[col] - 2*dot; argmin (first-min tiebreak); plain store
  float c2v0 = c2s[lc], c2v1 = c2s[16 + lc], c2v2 = c2s[32 + lc], c2v3 = c2s[48 + lc];
#pragma unroll
  for (int j = 0; j < 4; j++) {
    float bv = c2v0 - 2.f * acc0[j];
    int bi = lc;
    float v1 = c2v1 - 2.f * acc1[j];
    if (v1 < bv) { bv = v1; bi = 16 + lc; }
    float v2 = c2v2 - 2.f * acc2[j];
    if (v2 < bv) { bv = v2; bi = 32 + lc; }
    float v3 = c2v3 - 2.f * acc3[j];
    if (v3 < bv) { bv = v3; bi = 48 + lc; }
#pragma unroll
    for (int mask = 1; mask < 16; mask <<= 1) {
      float ov = __shfl_xor(bv, mask);
      int oi = __shfl_xor(bi, mask);
      if (ov < bv || (ov == bv && oi < bi)) { bv = ov; bi = oi; }
    }
    if (lc == 0) assign[n0 + w * 16 + lk * 4 + j] = bi;
  }
}

// Node 2: fine distances via fp16 MFMA, fully self-scheduling.
// Per block: LDS histogram of assign[] -> (k,tile) map -> rank-scan gather
// list -> 32f x 128m MFMA tile (double-buffered swizzled LDS) -> min -> out.
__global__ void __launch_bounds__(256) fine_mfma_kernel(
    const ush* __restrict__ feat_h, const ush* __restrict__ fine_h,
    const float* __restrict__ f2, const float* __restrict__ p2,
    const int* __restrict__ assign, float* __restrict__ out) {
  __shared__ int hist[64];
  __shared__ int meta[3];
  __shared__ int wsum[4];
  __shared__ int glist[32];
  __shared__ ush Ab[2][32 * 64];
  __shared__ ush Bb[2][128 * 64];
  __shared__ float red[32][5];

  int t = threadIdx.x, bid = blockIdx.x;
  int l = t & 63, w = t >> 6;

  if (t < 64) hist[t] = 0;
  __syncthreads();
#pragma unroll
  for (int j = 0; j < 32; j++) {
    int a = assign[t + j * 256];
    atomicAdd(&hist[a], 1);
  }
  __syncthreads();
  if (t < 64) {
    int c = hist[t];
    int nt = (c + TFT - 1) / TFT;
    int s2 = nt;
#pragma unroll
    for (int o = 1; o < 64; o <<= 1) {
      int v = __shfl_up(s2, o);
      if (t >= o) s2 += v;
    }
    int tb = s2 - nt;
    if (t == 63) meta[2] = s2;
    if (bid >= tb && bid < tb + nt) { meta[0] = t; meta[1] = bid - tb; }
  }
  __syncthreads();
  if (bid >= meta[2]) return;
  int k = meta[0], tile = meta[1];
  int nk = hist[k];
  int f0 = tile * TFT;
  int nf = min(TFT, nk - f0);

  // rank-scan: build this tile's gather list (fixed strided order)
  int cntk = 0;
#pragma unroll
  for (int j = 0; j < 32; j++) cntk += (assign[t + j * 256] == k) ? 1 : 0;
  int inc = cntk;
#pragma unroll
  for (int o = 1; o < 64; o <<= 1) {
    int v = __shfl_up(inc, o);
    if (l >= o) inc += v;
  }
  if (l == 63) wsum[w] = inc;
  __syncthreads();
  int rank = inc - cntk;
#pragma unroll
  for (int w2 = 0; w2 < 4; w2++) rank += (w2 < w) ? wsum[w2] : 0;
#pragma unroll
  for (int j = 0; j < 32; j++) {
    int i = t + j * 256;
    if (assign[i] == k) {
      int rr = rank - f0;
      if (rr >= 0 && rr < TFT) glist[rr] = i;
      rank++;
    }
  }
  __syncthreads();

  int sl8 = l >> 3, sl7 = l & 7;
  int slotw = sl7 ^ sl8;

  int arow = w * 8 + sl8;
  int agidx = glist[min(arow, nf - 1)];
  const ush* asrc = feat_h + (size_t)agidx * DIM + sl7 * 8;
  int aoff = arow * 64 + slotw * 8;
  int brow0 = w * 32 + 0 * 8 + sl8;
  int brow1 = w * 32 + 1 * 8 + sl8;
  int brow2 = w * 32 + 2 * 8 + sl8;
  int brow3 = w * 32 + 3 * 8 + sl8;
  const ush* bsrc0 = fine_h + ((size_t)k * MF + brow0) * DIM + sl7 * 8;
  const ush* bsrc1 = fine_h + ((size_t)k * MF + brow1) * DIM + sl7 * 8;
  const ush* bsrc2 = fine_h + ((size_t)k * MF + brow2) * DIM + sl7 * 8;
  const ush* bsrc3 = fine_h + ((size_t)k * MF + brow3) * DIM + sl7 * 8;
  int boff0 = brow0 * 64 + slotw * 8;
  int boff1 = brow1 * 64 + slotw * 8;
  int boff2 = brow2 * 64 + slotw * 8;
  int boff3 = brow3 * 64 + slotw * 8;

  int lc = l & 15, lk = l >> 4;
  int sx0 = (lk ^ sl7) * 8;
  int eA0 = lc * 64, eA1 = (16 + lc) * 64;
  int eB0 = (w * 32 + lc) * 64, eB1 = (w * 32 + 16 + lc) * 64;

  float p2v0 = p2[k * MF + w * 32 + lc];
  float p2v1 = p2[k * MF + w * 32 + 16 + lc];

  f32x4 acc00 = {0.f, 0.f, 0.f, 0.f}, acc01 = acc00, acc10 = acc00, acc11 = acc00;

  uint4 sA = *(const uint4*)asrc;
  uint4 sB0 = *(const uint4*)bsrc0;
  uint4 sB1 = *(const uint4*)bsrc1;
  uint4 sB2 = *(const uint4*)bsrc2;
  uint4 sB3 = *(const uint4*)bsrc3;
  *(uint4*)&Ab[0][aoff] = sA;
  *(uint4*)&Bb[0][boff0] = sB0;
  *(uint4*)&Bb[0][boff1] = sB1;
  *(uint4*)&Bb[0][boff2] = sB2;
  *(uint4*)&Bb[0][boff3] = sB3;
  __syncthreads();

  for (int c = 0; c < NCH; c++) {
    int cur = c & 1;
    if (c + 1 < NCH) {
      int go = (c + 1) * BKC;
      sA = *(const uint4*)(asrc + go);
      sB0 = *(const uint4*)(bsrc0 + go);
      sB1 = *(const uint4*)(bsrc1 + go);
      sB2 = *(const uint4*)(bsrc2 + go);
      sB3 = *(const uint4*)(bsrc3 + go);
    }
#pragma unroll
    for (int ksub = 0; ksub < 2; ksub++) {
      int sx = sx0 ^ (ksub * 32);
      f16x8 a0 = *(const f16x8*)&Ab[cur][eA0 + sx];
      f16x8 a1 = *(const f16x8*)&Ab[cur][eA1 + sx];
      f16x8 b0 = *(const f16x8*)&Bb[cur][eB0 + sx];
      f16x8 b1 = *(const f16x8*)&Bb[cur][eB1 + sx];
      acc00 = __builtin_amdgcn_mfma_f32_16x16x32_f16(a0, b0, acc00, 0, 0, 0);
      acc01 = __builtin_amdgcn_mfma_f32_16x16x32_f16(a0, b1, acc01, 0, 0, 0);
      acc10 = __builtin_amdgcn_mfma_f32_16x16x32_f16(a1, b0, acc10, 0, 0, 0);
      acc11 = __builtin_amdgcn_mfma_f32_16x16x32_f16(a1, b1, acc11, 0, 0, 0);
    }
    if (c + 1 < NCH) {
      int nb = cur ^ 1;
      *(uint4*)&Ab[nb][aoff] = sA;
      *(uint4*)&Bb[nb][boff0] = sB0;
      *(uint4*)&Bb[nb][boff1] = sB1;
      *(uint4*)&Bb[nb][boff2] = sB2;
      *(uint4*)&Bb[nb][boff3] = sB3;
    }
    __syncthreads();
  }

  float v0[4], v1[4];
#pragma unroll
  for (int j = 0; j < 4; j++) {
    v0[j] = fminf(p2v0 - 2.f * acc00[j], p2v1 - 2.f * acc01[j]);
    v1[j] = fminf(p2v0 - 2.f * acc10[j], p2v1 - 2.f * acc11[j]);
  }
#pragma unroll
  for (int mask = 1; mask < 16; mask <<= 1) {
#pragma unroll
    for (int j = 0; j < 4; j++) {
      v0[j] = fminf(v0[j], __shfl_xor(v0[j], mask));
      v1[j] = fminf(v1[j], __shfl_xor(v1[j], mask));
    }
  }
  if (lc == 0) {
#pragma unroll
    for (int j = 0; j < 4; j++) {
      red[lk * 4 + j][w] = v0[j];
      red[16 + lk * 4 + j][w] = v1[j];
    }
  }
  __syncthreads();
  if (t < 64) {
    float val = 0.f;
    if (t < nf) {
      float m = fminf(fminf(red[t][0], red[t][1]), fminf(red[t][2], red[t][3]));
      float d2 = f2[glist[t]] + m;
      val = sqrtf(fmaxf(d2, 0.f)) * (1.0f / (float)N_FEAT);
    }
    val = wave_reduce_sum(val);
    if (t == 0) atomicAdd(out, val);
  }
}

extern "C" void kernel_launch(void* const* d_in, const int* in_sizes, int n_in,
                              void* d_out, int out_size, void* d_ws, size_t ws_size,
                              hipStream_t stream) {
  (void)in_sizes; (void)n_in; (void)out_size; (void)ws_size;
  const float* feat   = (const float*)d_in[0];
  const float* coarse = (const float*)d_in[1];
  const float* fine   = (const float*)d_in[2];
  float* out = (float*)d_out;

  ush* feat_h = (ush*)d_ws;                          // 8192*512
  ush* fine_h = feat_h + (size_t)N_FEAT * DIM;       // 8192*512
  float* f2   = (float*)(fine_h + (size_t)KC * MF * DIM);  // 8192
  float* p2   = f2 + N_FEAT;                // 8192
  int* assign = (int*)(p2 + KC * MF);       // 8192

  fused_prep_assign_kernel<<<256, 256, 0, stream>>>(
      feat, coarse, fine, feat_h, fine_h, f2, p2, assign, out);
  fine_mfma_kernel<<<MAXTILES, 256, 0, stream>>>(feat_h, fine_h, f2, p2,
                                                 assign, out);
}